// Round 9
// baseline (74.906 us; speedup 1.0000x reference)
//
#include <hip/hip_runtime.h>
#include <hip/hip_cooperative_groups.h>
#include <cstddef>

namespace cg = cooperative_groups;

// Problem constants (from reference)
constexpr int Bn = 64;     // batch
constexpr int In = 2048;   // input capsules
constexpr int Dk = 8;      // input dim
constexpr int Kc = 16;     // output capsules
constexpr int En = 16;     // output dim
constexpr float EPS = 1e-7f;

// Decomposition: block = (p, g) tile of 16 i's x 8 batches; wave owns 2
// batches x all 16 i's -> disjoint outputs per wave -> barrier-free iter.
// IB=16 halves P (vs R8) -> partial buffer 16.8 MB -> 8.4 MB: less HBM
// round-trip traffic between iter and reduce phases.
constexpr int IB   = 16;           // i's per block
constexpr int P    = In / IB;      // 128 i-chunks
constexpr int BSET = 8;            // batches per block (2 per wave)
constexpr int NBG  = Bn / BSET;    // 8 batch groups
constexpr int BLOCKS = P * NBG;    // 1024 = 4 blocks/CU co-resident
constexpr int NXCD = 8;
constexpr int PPX  = P / NXCD;     // 16 p-chunks per XCD (2 MB of W < 4 MB L2)

// DPP cross-lane add on the VALU pipe (no LDS-pipe traffic).
// ctrl: 0xB1 = quad_perm [1,0,3,2] (xor 1), 0x4E = quad_perm [2,3,0,1] (xor 2),
//       0x124 = row_ror:4, 0x128 = row_ror:8 (16-lane rows)
template<int CTRL>
__device__ __forceinline__ float dpp_add(float v) {
    int r = __builtin_amdgcn_update_dpp(0, __float_as_int(v), CTRL, 0xF, 0xF, true);
    return v + __int_as_float(r);
}

// One routing iteration for a (p, g) tile. x tile staged in smemx[0,1024) as
// [bl][il][d]. Wave wv handles batches bw..bw+1 across all 16 i's; acc[2] =
// 8 VGPR live (R4/R5 lesson: keep the live set structurally small, never via
// launch_bounds caps). vsum slice in 2 registers/lane from the L2-resident
// v-buffer. Barrier-free; one plain float4 store per (batch, lane).
template<bool UNIFORM>
__device__ __forceinline__ void iter_body(const float* __restrict__ smemx,
        const float* __restrict__ W, const float* __restrict__ vsg,
        float* __restrict__ partial, int p, int b0, int i0, int t)
{
    const int lane = t & 63;
    const int wv   = t >> 6;
    const int k    = lane >> 2;             // output capsule
    const int e4   = (lane & 3) << 2;       // first of 4 output dims
    const int bw   = b0 + (wv << 1);        // this wave's first batch

    float4 vb[2];
    if (!UNIFORM) {
        #pragma unroll
        for (int b4 = 0; b4 < 2; ++b4)
            vb[b4] = *(const float4*)(vsg + ((bw + b4) << 8) + k * 16 + e4);
    }

    float4 acc[2];
    #pragma unroll
    for (int b4 = 0; b4 < 2; ++b4) acc[b4] = make_float4(0.f, 0.f, 0.f, 0.f);

    #pragma unroll 1
    for (int ii = 0; ii < IB; ++ii) {
        const int i = i0 + ii;
        const float* wp = W + (size_t)i * (Kc * Dk * En) + k * (Dk * En) + e4;
        float4 w[8];
        #pragma unroll
        for (int d = 0; d < 8; ++d) w[d] = *(const float4*)(wp + d * En);

        #pragma unroll
        for (int b4 = 0; b4 < 2; ++b4) {
            const int bl = (wv << 1) + b4;
            const float* xp = smemx + (((bl << 4) + ii) << 3);  // [bl][ii][*]
            const float4 x0 = *(const float4*)xp;
            const float4 x1 = *(const float4*)(xp + 4);
            const float xs8[8] = {x0.x, x0.y, x0.z, x0.w, x1.x, x1.y, x1.z, x1.w};

            float4 uh = make_float4(0.f, 0.f, 0.f, 0.f);
            #pragma unroll
            for (int d = 0; d < 8; ++d) {
                uh.x = fmaf(xs8[d], w[d].x, uh.x);
                uh.y = fmaf(xs8[d], w[d].y, uh.y);
                uh.z = fmaf(xs8[d], w[d].z, uh.z);
                uh.w = fmaf(xs8[d], w[d].w, uh.w);
            }

            if (UNIFORM) {
                acc[b4].x += uh.x; acc[b4].y += uh.y;
                acc[b4].z += uh.z; acc[b4].w += uh.w;
            } else {
                float tt = uh.x * vb[b4].x + uh.y * vb[b4].y
                         + uh.z * vb[b4].z + uh.w * vb[b4].w;
                tt = dpp_add<0xB1>(tt);           // e-reduce: quad xor 1
                tt = dpp_add<0x4E>(tt);           // e-reduce: quad xor 2
                const float pe = __expf(tt);      // no max-sub: |tt| small
                float den = dpp_add<0x124>(pe);   // k-sum in row: ror 4
                den = dpp_add<0x128>(den);        // k-sum in row: ror 8
                den += __shfl_xor(den, 16);       // cross-row
                den += __shfl_xor(den, 32);
                const float c = pe * __builtin_amdgcn_rcpf(den);
                acc[b4].x = fmaf(c, uh.x, acc[b4].x);
                acc[b4].y = fmaf(c, uh.y, acc[b4].y);
                acc[b4].z = fmaf(c, uh.z, acc[b4].z);
                acc[b4].w = fmaf(c, uh.w, acc[b4].w);
            }
        }
    }

    #pragma unroll
    for (int b4 = 0; b4 < 2; ++b4)
        *(float4*)(partial + ((size_t)(bw + b4) * P + p) * 256 + k * 16 + e4) = acc[b4];
}

// Sum the P=128 partials, squash, optional vprev add. rb = 0..255:
// b = rb>>2, element-quarter q = rb&3. 4 p-groups of 32 p's per thread-group,
// combined via smem[1024,1280).
__device__ __forceinline__ void reduce_phase(float* smem,
        const float* __restrict__ partial, float scale,
        const float* __restrict__ vprev, float* __restrict__ vout, int rb, int t)
{
    const int b  = rb >> 2;
    const int q  = rb & 3;
    const int t4 = t & 63;
    const int pg = t >> 6;
    const int el = (q << 6) + t4;           // element 0..255 (= k*16+e)
    const float* pp = partial + (size_t)b * (P * 256) + ((pg << 5) * 256) + el;

    float s0 = 0.f, s1 = 0.f, s2 = 0.f, s3 = 0.f;
    #pragma unroll 4
    for (int j = 0; j < 32; j += 4) {
        s0 += pp[(j + 0) * 256];
        s1 += pp[(j + 1) * 256];
        s2 += pp[(j + 2) * 256];
        s3 += pp[(j + 3) * 256];
    }
    float* red = smem + 1024;
    red[(pg << 6) + t4] = (s0 + s1) + (s2 + s3);
    __syncthreads();

    if (t < 64) {
        const float val = (red[t4] + red[64 + t4] + red[128 + t4] + red[192 + t4]) * scale;
        float sq = val * val;                // e = el & 15 = t4 & 15
        sq += __shfl_xor(sq, 1);
        sq += __shfl_xor(sq, 2);
        sq += __shfl_xor(sq, 4);
        sq += __shfl_xor(sq, 8);
        const float f = sq / ((1.0f + sq) * sqrtf(sq + EPS));
        float v = val * f;
        if (vprev) v += vprev[(b << 8) + el];
        vout[(b << 8) + el] = v;
    }
    __syncthreads();
}

// XCD-bijective tile mapping: physical XCD = bid&7 (round-robin dispatch);
// each XCD owns a contiguous 16-chunk p-range (2 MB of W -> L2-resident) and
// all 8 batch-group duplicates of a p run on the same XCD.
__device__ __forceinline__ void tile_map(int bid, int& p, int& b0, int& i0) {
    const int xcd = bid & 7;
    const int j   = bid >> 3;               // 0..127
    p  = xcd * PPX + (j & (PPX - 1));       // bijective: 8 x 16 x 8 = 1024
    b0 = (j >> 4) * BSET;                   // 0..7 batch groups
    i0 = p * IB;
}

// Stage x[b0..b0+7][i0..i0+15][0..7] -> smem [bl][il][d] (256 float4).
__device__ __forceinline__ void stage_x(float* smem, const float* __restrict__ x,
                                        int b0, int i0, int t) {
    const int bl = t >> 5;                  // 0..7
    const int r  = t & 31;                  // float4 within the 128-float row
    ((float4*)smem)[t] = *(const float4*)(x + ((size_t)(b0 + bl) * In + i0) * Dk + (r << 2));
}

// ---------------- fused cooperative kernel (5 KB LDS) ----------------
__global__ __launch_bounds__(256)
void caps_fused(const float* __restrict__ x, const float* __restrict__ W,
                float* __restrict__ partial, float* __restrict__ v0,
                float* __restrict__ vs, float* __restrict__ out)
{
    cg::grid_group grid = cg::this_grid();
    __shared__ __align__(16) float smem[1280];   // x [0,1024) | red [1024,1280)

    const int t = threadIdx.x, bid = blockIdx.x;
    int p, b0, i0;
    tile_map(bid, p, b0, i0);

    stage_x(smem, x, b0, i0, t);        // once, reused by all 3 iterations
    __syncthreads();

    // r = 0: uniform coupling (1/16 folded into reduce scale)
    iter_body<true>(smem, W, nullptr, partial, p, b0, i0, t);
    grid.sync();
    if (bid < 256) reduce_phase(smem, partial, 1.0f / 16.0f, nullptr, v0, bid, t);
    grid.sync();

    // r = 1: logits = dot(u_hat, v0);  vs = v0 + v1
    iter_body<false>(smem, W, v0, partial, p, b0, i0, t);
    grid.sync();
    if (bid < 256) reduce_phase(smem, partial, 1.0f, v0, vs, bid, t);
    grid.sync();

    // r = 2: logits = dot(u_hat, v0 + v1); final squash -> out
    iter_body<false>(smem, W, vs, partial, p, b0, i0, t);
    grid.sync();
    if (bid < 256) reduce_phase(smem, partial, 1.0f, nullptr, out, bid, t);
}

// ---------------- fallback: same phases as separate kernels ----------------
template<bool UNIFORM>
__global__ __launch_bounds__(256)
void caps_iter_g(const float* __restrict__ x, const float* __restrict__ W,
                 const float* __restrict__ vsg, float* __restrict__ partial)
{
    __shared__ __align__(16) float smem[1280];
    const int t = threadIdx.x;
    int p, b0, i0;
    tile_map(blockIdx.x, p, b0, i0);
    stage_x(smem, x, b0, i0, t);
    __syncthreads();
    iter_body<UNIFORM>(smem, W, vsg, partial, p, b0, i0, t);
}

__global__ __launch_bounds__(256)
void caps_reduce_g(const float* __restrict__ partial, float scale,
                   const float* __restrict__ vprev, float* __restrict__ vout)
{
    __shared__ __align__(16) float smem[1280];
    reduce_phase(smem, partial, scale, vprev, vout, blockIdx.x, threadIdx.x);
}

extern "C" void kernel_launch(void* const* d_in, const int* in_sizes, int n_in,
                              void* d_out, int out_size, void* d_ws, size_t ws_size,
                              hipStream_t stream) {
    const float* x = (const float*)d_in[0];   // [64, 2048, 8]
    const float* W = (const float*)d_in[1];   // [2048, 16, 8, 16]
    float* out = (float*)d_out;               // [64, 16, 16]
    float* ws  = (float*)d_ws;

    float* v0      = ws;                      // [64,16,16]
    float* vs      = ws + 16384;              // v0 + v1
    float* partial = ws + 32768;              // [64][128][256] = 8.4 MB

    // Host-side co-residency gate (capture-safe: no stream ops). Only launch
    // cooperatively if the runtime agrees all 1024 blocks fit.
    int dev = 0;
    hipGetDevice(&dev);
    int numCU = 0;
    hipDeviceGetAttribute(&numCU, hipDeviceAttributeMultiprocessorCount, dev);
    int maxB = 0;
    hipError_t oe = hipOccupancyMaxActiveBlocksPerMultiprocessor(
        &maxB, (const void*)caps_fused, 256, 0);
    const bool coop = (oe == hipSuccess) && numCU > 0 &&
                      ((long)maxB * numCU >= BLOCKS);

    if (coop) {
        void* args[] = { (void*)&x, (void*)&W, (void*)&partial,
                         (void*)&v0, (void*)&vs, (void*)&out };
        hipLaunchCooperativeKernel((void*)caps_fused, dim3(BLOCKS), dim3(256),
                                   args, 0, stream);
    } else {
        caps_iter_g<true ><<<BLOCKS, 256, 0, stream>>>(x, W, nullptr, partial);
        caps_reduce_g<<<256, 256, 0, stream>>>(partial, 1.0f / 16.0f, nullptr, v0);
        caps_iter_g<false><<<BLOCKS, 256, 0, stream>>>(x, W, v0, partial);
        caps_reduce_g<<<256, 256, 0, stream>>>(partial, 1.0f, v0, vs);
        caps_iter_g<false><<<BLOCKS, 256, 0, stream>>>(x, W, vs, partial);
        caps_reduce_g<<<256, 256, 0, stream>>>(partial, 1.0f, nullptr, out);
    }
}